// Round 2
// baseline (244.826 us; speedup 1.0000x reference)
//
#include <hip/hip_runtime.h>
#include <cmath>

#define DIM 384
#define IMG 112
#define IMG2 (IMG*IMG)          // 12544
#define FINALN 16
#define PATCH 49
#define SPST 50                 // padded LDS row stride (8B-aligned -> ds_read_b64)
#define DROP_P 0.2f

// One block per output patch (b,h,w). 2048 blocks x 512 threads.
// LDS: patch (384*50 fp32 = 76.8 KB) + partials (1.5 KB) -> 2 blocks/CU.
// v2: logits computed IN-REGISTER during staging drain (42 fma/lane) +
// wave shfl-reduce; the 392x48 ds_read logits phase and its barrier are gone.
// Output phase reads via ds_read_b64 (stride 50 keeps every row 8B-aligned).
__global__ __launch_bounds__(512, 4) void kFused(const float* __restrict__ hr,
                                                 const float* __restrict__ du,
                                                 const float* __restrict__ aw,
                                                 const float* __restrict__ ab,
                                                 const float* __restrict__ wmat,
                                                 const float* __restrict__ bmat,
                                                 float* __restrict__ out) {
    __shared__ float sp[DIM * SPST];    // patch, c-major: sp[c*50 + i*7 + j]
    __shared__ float s_red[8 * PATCH];  // per-wave partial logits, then attn

    int tid = threadIdx.x;

    // XCD-locality swizzle: batch b == XCD id; w-adjacent patches (sharing
    // 64B hr lines) are consecutive blocks on the same XCD L2.
    int id  = blockIdx.x;                 // 0..2047
    int nid = (id & 7) * 256 + (id >> 3);
    int b = nid >> 8;
    int h = (nid >> 4) & 15;
    int w = nid & 15;

    // ---- tiny scalars for wave 0 (softmax finalize) ----
    float duv = 0.f, abv = 0.f, wv = 0.f, bv = 0.f;
    if (tid < 64) {
        if (tid < PATCH) { wv = wmat[tid]; bv = bmat[tid]; }
        duv = du[(b << 8) + (h << 4) + w];
        abv = ab[0];
    }

    // ---- staging map: group g = tid>>3 owns channels 6g..6g+5, lane j = col ----
    int g = tid >> 3;                 // 0..63
    int j = tid & 7;                  // 0..7 (7 = idle lane)
    const float* base = hr + (size_t)b * DIM * IMG2 + (size_t)(7 * h) * IMG + 7 * w;
    const float* gp = base + (size_t)g * 6 * IMG2 + j;

    // aw for this lane's 6 channels (uniform across the 8-lane group -> L2 broadcast)
    float awr[6];
    #pragma unroll
    for (int cc = 0; cc < 6; ++cc) awr[cc] = aw[g * 6 + cc];

    // ---- stage patch + in-register partial logits ----
    // part[s] = sum_cc v[cc,s] * aw[6g+cc]  (p = s*7 + j)
    float part[7] = {0.f, 0.f, 0.f, 0.f, 0.f, 0.f, 0.f};
    if (j < 7) {
        float v[42];
        #pragma unroll
        for (int it = 0; it < 42; ++it) {
            const int cc = it / 7, s = it % 7;          // compile-time
            v[it] = gp[(size_t)cc * IMG2 + s * IMG];
        }
        float* lp = sp + g * 6 * SPST + j;
        #pragma unroll
        for (int it = 0; it < 42; ++it) {
            const int cc = it / 7, s = it % 7;
            lp[cc * SPST + s * 7] = v[it];
            part[s] = fmaf(v[it], awr[cc], part[s]);
        }
    }

    // reduce partial logits across the wave's 8 channel-groups (lane bits 3..5;
    // xor masks 8/16/32 preserve j, so idle j==7 lanes never contaminate)
    #pragma unroll
    for (int s = 0; s < 7; ++s) {
        part[s] += __shfl_xor(part[s], 8, 64);
        part[s] += __shfl_xor(part[s], 16, 64);
        part[s] += __shfl_xor(part[s], 32, 64);
    }
    int wave = tid >> 6, lane = tid & 63;
    if (lane < 7) {                      // lane = j (g&7==0): holds wave sums
        #pragma unroll
        for (int s = 0; s < 7; ++s)
            s_red[wave * PATCH + s * 7 + lane] = part[s];
    }
    __syncthreads();

    // ---- wave 0: finalize logits (sum 8 wave-partials), masked affine, softmax ----
    if (tid < 64) {
        float al = -1e30f;
        if (tid < PATCH) {
            float logit = abv;
            #pragma unroll
            for (int gg = 0; gg < 8; ++gg) logit += s_red[gg * PATCH + tid];
            float mask = (duv > DROP_P) ? 1.0f : 0.0f;
            al = fmaf(logit * mask, wv, bv);
        }
        float m = al;
        #pragma unroll
        for (int d = 32; d >= 1; d >>= 1) m = fmaxf(m, __shfl_xor(m, d, 64));
        float e = (tid < PATCH) ? __expf(al - m) : 0.f;
        float s = e;
        #pragma unroll
        for (int d = 32; d >= 1; d >>= 1) s += __shfl_xor(s, d, 64);
        if (tid < PATCH) s_red[tid] = e / s;   // attn (overwrites after reads)
    }
    __syncthreads();

    // ---- output: thread -> channel; ds_read_b64 pairs (rows 8B-aligned),
    //      s_red[p] same-address broadcast (free) ----
    if (tid < DIM) {
        const float* pc = sp + tid * SPST;
        float acc = 0.f;
        #pragma unroll
        for (int k = 0; k < 24; ++k) {
            float2 v2 = *reinterpret_cast<const float2*>(pc + 2 * k);
            acc = fmaf(v2.x, s_red[2 * k],     acc);
            acc = fmaf(v2.y, s_red[2 * k + 1], acc);
        }
        acc = fmaf(pc[48], s_red[48], acc);
        out[(((size_t)b * DIM + tid) * FINALN + h) * FINALN + w] = acc;
    }
}

extern "C" void kernel_launch(void* const* d_in, const int* in_sizes, int n_in,
                              void* d_out, int out_size, void* d_ws, size_t ws_size,
                              hipStream_t stream) {
    const float* hr   = (const float*)d_in[0];
    // d_in[1] = guidance (unused by reference)
    const float* du   = (const float*)d_in[2];
    const float* aw   = (const float*)d_in[3];
    const float* ab   = (const float*)d_in[4];
    const float* wmat = (const float*)d_in[5];
    const float* bmat = (const float*)d_in[6];
    float* out = (float*)d_out;

    kFused<<<2048, 512, 0, stream>>>(hr, du, aw, ab, wmat, bmat, out);
}